// Round 1
// baseline (1668.123 us; speedup 1.0000x reference)
//
#include <hip/hip_runtime.h>
#include <math.h>

typedef __bf16 bf16;
typedef bf16 bf16x8 __attribute__((ext_vector_type(8)));
typedef bf16 bf16x4_t __attribute__((ext_vector_type(4)));
typedef float f32x4 __attribute__((ext_vector_type(4)));

// B=8, H=W=64, DIM=512, WS=8, SHIFT=4, NH=16, HD=32, N=64, nW=64, M=32768
// NE=4, HID=2048, GH=256. Inputs f32 (proven R2->R3), output f32 (proven R3->R4).

#define EPI_QKV  0
#define EPI_PROJ 1
#define EPI_BF16 2
#define EPI_RELU 3
#define EPI_F32  4
#define EPI_GELU 5
#define EPI_MOE  6

#define NIN 26

#define GLDS16(gp, lp)                                                    \
    __builtin_amdgcn_global_load_lds(                                     \
        (const __attribute__((address_space(1))) void*)(gp),              \
        (__attribute__((address_space(3))) void*)(lp), 16, 0, 0)

// ---------------- dtype probe ---------------------------------------------------
__global__ __launch_bounds__(256) void probe_k(const unsigned short* __restrict__ x,
                                               int* __restrict__ flag)
{
    __shared__ int cnt[256];
    int t = threadIdx.x;
    int bad = 0;
    for (int j = t; j < 4096; j += 256) {
        int e = (x[j] >> 7) & 0xFF;
        if (e >= 132) bad++;
    }
    cnt[t] = bad;
    __syncthreads();
    for (int s = 128; s > 0; s >>= 1) {
        if (t < s) cnt[t] += cnt[t + s];
        __syncthreads();
    }
    if (t == 0) *flag = (cnt[0] > 64) ? 1 : 0;
}

// ---------------- convert all inputs to bf16 in ws ------------------------------
struct ConvArgs {
    const void* src[NIN];
    bf16* dst[NIN];
    int n[NIN];
};

__global__ __launch_bounds__(256) void conv_k(ConvArgs a, const int* __restrict__ flag)
{
    int i = blockIdx.y;
    int n4 = a.n[i] >> 2;
    bf16x4_t* dst = (bf16x4_t*)a.dst[i];
    int stride = gridDim.x * 256;
    if (*flag) {
        const float4* s = (const float4*)a.src[i];
        for (int j = blockIdx.x * 256 + threadIdx.x; j < n4; j += stride) {
            float4 v = s[j];
            dst[j] = (bf16x4_t){(bf16)v.x, (bf16)v.y, (bf16)v.z, (bf16)v.w};
        }
    } else {
        const bf16x4_t* s = (const bf16x4_t*)a.src[i];
        for (int j = blockIdx.x * 256 + threadIdx.x; j < n4; j += stride)
            dst[j] = s[j];
    }
}

// ---------------- zero f32 buffer -----------------------------------------------
__global__ __launch_bounds__(256) void zero_k(float4* __restrict__ p, int n4)
{
    int stride = gridDim.x * 256;
    for (int j = blockIdx.x * 256 + threadIdx.x; j < n4; j += stride)
        p[j] = (float4){0.f, 0.f, 0.f, 0.f};
}

// shift + window-partition row map (self-inverse composition: roll -4 then +4)
__device__ __forceinline__ int win_remap(int r) {
    int win = r >> 6, tok = r & 63;
    int b = win >> 6, wi = win & 63;
    int h = (((wi >> 3) << 3) + (tok >> 3) + 4) & 63;
    int w = (((wi & 7) << 3) + (tok & 7) + 4) & 63;
    return (b << 12) | (h << 6) | w;
}

// ---------------- MFMA GEMM, BK=64, swizzled LDS, XCD-aware grid ----------------
// C[m][n] = sum_k A[m][k]*W[n][k] (+epilogue). 128x128 tile, 4 waves 2x2.
// LDS tile: slot (row, cl) holds global chunk cg = cl ^ (row&7) (16B chunks).
// SPLITK=2: grid doubled, upper half handles K/2..K, f32-atomic accumulation.
template<int REMAP_A, int EPI, int SPLITK = 1>
__global__ __launch_bounds__(256) void gemm_k(
    const bf16* __restrict__ A, const bf16* __restrict__ Bw,
    void* __restrict__ Cout,
    const bf16* __restrict__ bias, const bf16* __restrict__ bias2,
    const float* __restrict__ wts, int N, int K, int eIdx, int nbm)
{
    __shared__ __attribute__((aligned(16))) bf16 As[128 * 64];
    __shared__ __attribute__((aligned(16))) bf16 Bs[128 * 64];
    const int tid = threadIdx.x;

    // XCD-aware swizzle: xcd = lin&7 gets bm = xcd+8*(...), sweeping bn fastest
    // over groups of G A-tiles -> per-XCD A-tile L2 reuse across the bn sweep.
    int lin = blockIdx.x;
    int ksp = 0;
    if constexpr (SPLITK == 2) {
        int half = gridDim.x >> 1;
        if (lin >= half) { ksp = 1; lin -= half; }
    }
    const int nbn = N >> 7;
    const int xcd = lin & 7, s = lin >> 3;
    const int nbmx = nbm >> 3;
    const int G = nbmx < 16 ? nbmx : 16;
    const int gsz = G * nbn;
    const int gi = s / gsz, rem = s - gi * gsz;
    const int bn = rem / G, bmi = rem - bn * G;
    const int bm = xcd + 8 * (gi * G + bmi);

    const int wave = tid >> 6, lane = tid & 63;
    const int wm = (wave >> 1) << 6, wn = (wave & 1) << 6;
    const int lrow = lane & 15, quad = lane >> 4;

    // staging: thread -> (row sr=tid>>3 [+32*i], LDS chunk slot sc=tid&7);
    // fetches global chunk scg = sc ^ (sr&7). LDS dest = i*4096B + tid*16B.
    const int sr = tid >> 3, sc = tid & 7;
    const int scg = sc ^ (sr & 7);
    int ga[4];
#pragma unroll
    for (int i = 0; i < 4; i++) {
        int r = bm * 128 + sr + i * 32;
        ga[i] = REMAP_A ? win_remap(r) : r;
    }
    const int brow = bn * 128 + sr;
    bf16* lA = As + tid * 8;
    bf16* lB = Bs + tid * 8;

    f32x4 acc[4][4];
#pragma unroll
    for (int i = 0; i < 4; i++)
#pragma unroll
        for (int j = 0; j < 4; j++) acc[i][j] = (f32x4){0.f, 0.f, 0.f, 0.f};

    int kbeg = 0, kend = K;
    if constexpr (SPLITK == 2) {
        int kh = K >> 1;
        kbeg = ksp * kh;
        kend = kbeg + kh;
    }
    for (int k0 = kbeg; k0 < kend; k0 += 64) {
        __syncthreads();
#pragma unroll
        for (int i = 0; i < 4; i++) {
            GLDS16(A + (size_t)ga[i] * K + k0 + scg * 8, lA + i * 2048);
            GLDS16(Bw + (size_t)(brow + i * 32) * K + k0 + scg * 8, lB + i * 2048);
        }
        __syncthreads();
#pragma unroll
        for (int ks = 0; ks < 2; ks++) {
            bf16x8 af[4], bfr[4];
#pragma unroll
            for (int t = 0; t < 4; t++) {
                int ra = wm + t * 16 + lrow;
                af[t] = *(const bf16x8*)(&As[ra * 64 + (((ks << 2) + quad) ^ (ra & 7)) * 8]);
                int rb = wn + t * 16 + lrow;
                bfr[t] = *(const bf16x8*)(&Bs[rb * 64 + (((ks << 2) + quad) ^ (rb & 7)) * 8]);
            }
#pragma unroll
            for (int tm = 0; tm < 4; tm++)
#pragma unroll
                for (int tn = 0; tn < 4; tn++)
                    acc[tm][tn] = __builtin_amdgcn_mfma_f32_16x16x32_bf16(
                        af[tm], bfr[tn], acc[tm][tn], 0, 0, 0);
        }
    }

    const int cr0 = quad << 2, cc0 = lane & 15;
#pragma unroll
    for (int tm = 0; tm < 4; tm++) {
#pragma unroll
        for (int tn = 0; tn < 4; tn++) {
#pragma unroll
            for (int r = 0; r < 4; r++) {
                int row = bm * 128 + wm + tm * 16 + cr0 + r;
                int col = bn * 128 + wn + tn * 16 + cc0;
                float v = acc[tm][tn][r];
                if constexpr (EPI == EPI_QKV) {
                    float bv = 0.f;
                    if (col < 512) bv = (float)bias[col];
                    else if (col >= 1024) bv = (float)bias2[col - 1024];
                    ((bf16*)Cout)[(size_t)row * N + col] = (bf16)(v + bv);
                } else if constexpr (EPI == EPI_PROJ) {
                    v += (float)bias[col];
                    ((bf16*)Cout)[(size_t)win_remap(row) * N + col] = (bf16)v;
                } else if constexpr (EPI == EPI_BF16) {
                    v += (float)bias[col];
                    ((bf16*)Cout)[(size_t)row * N + col] = (bf16)v;
                } else if constexpr (EPI == EPI_RELU) {
                    v += (float)bias[col];
                    ((bf16*)Cout)[(size_t)row * N + col] = (bf16)fmaxf(v, 0.f);
                } else if constexpr (EPI == EPI_F32) {
                    v += (float)bias[col];
                    ((float*)Cout)[(size_t)row * N + col] = v;
                } else if constexpr (EPI == EPI_GELU) {
                    // hid = wts[row,e] * gelu(v + b1); wts folded here so the
                    // second gemm is a pure accumulation.
                    // tanh-form GELU: x*sigmoid(1.5957691*x*(1+0.044715*x^2)),
                    // branch-free, ~8 VALU + v_exp + v_rcp (erff was ~4x this
                    // and made the epilogue VALU pipe exceed mainloop MFMA).
                    v += (float)bias[col];
                    float u = 1.5957691216f * v * fmaf(0.044715f * v, v, 1.0f);
                    float g = v * __builtin_amdgcn_rcpf(1.0f + __expf(-u));
                    g *= wts[(size_t)row * 4 + eIdx];
                    ((bf16*)Cout)[(size_t)row * N + col] = (bf16)g;
                } else if constexpr (EPI == EPI_MOE) {
                    // moe buffer zero-initialized by zero_k; all expert /
                    // split-K contributions accumulate via device-scope f32
                    // atomics (race-free across the 2 K-halves in-flight).
                    atomicAdd(&((float*)Cout)[(size_t)row * N + col], v);
                }
            }
        }
    }
}

// ---------------- CPB table -----------------------------------------------------
__global__ __launch_bounds__(64) void cpb_k(const bf16* __restrict__ w1,
                                            const bf16* __restrict__ b1,
                                            const bf16* __restrict__ w2,
                                            float* __restrict__ tbl)
{
    int e = blockIdx.x;
    int d0 = e / 15, d1 = e % 15;
    auto f = [](int d) -> float {
        float v = (float)(d - 7) * (8.0f / 7.0f);
        float t = log2f(fabsf(v) + 1.0f) * (1.0f / 3.0f);
        return v < 0.f ? -t : (v > 0.f ? t : 0.0f);
    };
    float t0 = f(d0), t1 = f(d1);
    __shared__ float hsh[512];
    int tid = threadIdx.x;
    for (int j = tid; j < 512; j += 64) {
        float h = t0 * (float)w1[j * 2 + 0] + t1 * (float)w1[j * 2 + 1] + (float)b1[j];
        hsh[j] = fmaxf(h, 0.0f);
    }
    __syncthreads();
    if (tid < 16) {
        float sum = 0.f;
        for (int j = 0; j < 512; j++) sum += hsh[j] * (float)w2[tid * 512 + j];
        tbl[e * 16 + tid] = 16.0f / (1.0f + expf(-sum));
    }
}

// ---------------- MFMA attention (unchanged from R5) ----------------------------
#define PT 72
#define VT 72
__global__ __launch_bounds__(256) void attn_k(const bf16* __restrict__ qkv,
                                              const bf16* __restrict__ lsc,
                                              const float* __restrict__ tbl,
                                              bf16* __restrict__ aout)
{
    __shared__ __attribute__((aligned(16))) bf16 VtAll[4][32 * VT];
    __shared__ __attribute__((aligned(16))) bf16 PsAll[4][64 * PT];
    const int tid  = threadIdx.x;
    const int wave = tid >> 6, lane = tid & 63;
    const int pair = blockIdx.x * 4 + wave;
    const int win  = pair >> 4, head = pair & 15;
    bf16* Vt = VtAll[wave];
    bf16* Ps = PsAll[wave];

    const int lcol = lane & 15;
    const int quad = lane >> 4;
    const int lk   = quad << 3;

    const bf16* qbase = qkv + (size_t)(win * 64) * 1536 + head * 32;

    {
        const bf16* vp = qbase + (size_t)lane * 1536 + 1024;
        bf16x8 v0 = *(const bf16x8*)(vp);
        bf16x8 v1 = *(const bf16x8*)(vp + 8);
        bf16x8 v2 = *(const bf16x8*)(vp + 16);
        bf16x8 v3 = *(const bf16x8*)(vp + 24);
#pragma unroll
        for (int j = 0; j < 8; j++) {
            Vt[(j)      * VT + lane] = v0[j];
            Vt[(j + 8)  * VT + lane] = v1[j];
            Vt[(j + 16) * VT + lane] = v2[j];
            Vt[(j + 24) * VT + lane] = v3[j];
        }
    }

    bf16x8 qf[4], kf[4];
#pragma unroll
    for (int t = 0; t < 4; t++) {
        const bf16* qp = qbase + (size_t)(t * 16 + lcol) * 1536 + lk;
        bf16x8 q = *(const bf16x8*)qp;
        float ss = 0.f;
#pragma unroll
        for (int j = 0; j < 8; j++) { float f = (float)q[j]; ss += f * f; }
        ss += __shfl_xor(ss, 16); ss += __shfl_xor(ss, 32);
        float inv = 1.f / fmaxf(sqrtf(ss), 1e-12f);
#pragma unroll
        for (int j = 0; j < 8; j++) q[j] = (bf16)((float)q[j] * inv);
        qf[t] = q;

        const bf16* kp = qbase + (size_t)(t * 16 + lcol) * 1536 + 512 + lk;
        bf16x8 k = *(const bf16x8*)kp;
        ss = 0.f;
#pragma unroll
        for (int j = 0; j < 8; j++) { float f = (float)k[j]; ss += f * f; }
        ss += __shfl_xor(ss, 16); ss += __shfl_xor(ss, 32);
        inv = 1.f / fmaxf(sqrtf(ss), 1e-12f);
#pragma unroll
        for (int j = 0; j < 8; j++) k[j] = (bf16)((float)k[j] * inv);
        kf[t] = k;
    }

    f32x4 s[4][4];
#pragma unroll
    for (int tm = 0; tm < 4; tm++)
#pragma unroll
        for (int tn = 0; tn < 4; tn++) s[tm][tn] = (f32x4){0.f, 0.f, 0.f, 0.f};
#pragma unroll
    for (int tm = 0; tm < 4; tm++)
#pragma unroll
        for (int tn = 0; tn < 4; tn++)
            s[tm][tn] = __builtin_amdgcn_mfma_f32_16x16x32_bf16(
                qf[tm], kf[tn], s[tm][tn], 0, 0, 0);

    float scale = expf(fminf((float)lsc[head], 4.6051701860f));
    int wi = win & 63, wh = wi >> 3, ww = wi & 7;
    float rinv[4][4];
#pragma unroll
    for (int tm = 0; tm < 4; tm++) {
#pragma unroll
        for (int r = 0; r < 4; r++) {
            int m = tm * 16 + quad * 4 + r;
            int qi = m >> 3, qj = m & 7;
            int qh = wh * 8 + qi, qw = ww * 8 + qj;
            int qid = (qh < 56 ? 0 : (qh < 60 ? 1 : 2)) * 3 +
                      (qw < 56 ? 0 : (qw < 60 ? 1 : 2));
            float v[4]; float mx = -1e30f;
#pragma unroll
            for (int tn = 0; tn < 4; tn++) {
                int n = tn * 16 + lcol;
                int ki = n >> 3, kj = n & 7;
                int kh = wh * 8 + ki, kw = ww * 8 + kj;
                int kid = (kh < 56 ? 0 : (kh < 60 ? 1 : 2)) * 3 +
                          (kw < 56 ? 0 : (kw < 60 ? 1 : 2));
                float val = s[tm][tn][r] * scale
                          + tbl[((qi - ki + 7) * 15 + (qj - kj + 7)) * 16 + head];
                if (kid != qid) val -= 100.f;
                v[tn] = val;
                mx = fmaxf(mx, val);
            }
            mx = fmaxf(mx, __shfl_xor(mx, 1));
            mx = fmaxf(mx, __shfl_xor(mx, 2));
            mx = fmaxf(mx, __shfl_xor(mx, 4));
            mx = fmaxf(mx, __shfl_xor(mx, 8));
            float sum = 0.f;
#pragma unroll
            for (int tn = 0; tn < 4; tn++) {
                float p = expf(v[tn] - mx);
                v[tn] = p; sum += p;
            }
            sum += __shfl_xor(sum, 1);
            sum += __shfl_xor(sum, 2);
            sum += __shfl_xor(sum, 4);
            sum += __shfl_xor(sum, 8);
            rinv[tm][r] = 1.f / sum;
#pragma unroll
            for (int tn = 0; tn < 4; tn++)
                Ps[m * PT + tn * 16 + lcol] = (bf16)v[tn];
        }
    }
    __syncthreads();

    f32x4 o[4][2];
#pragma unroll
    for (int tm = 0; tm < 4; tm++)
#pragma unroll
        for (int tn = 0; tn < 2; tn++) o[tm][tn] = (f32x4){0.f, 0.f, 0.f, 0.f};
#pragma unroll
    for (int ks = 0; ks < 2; ks++) {
        bf16x8 af[4], vf[2];
#pragma unroll
        for (int tm = 0; tm < 4; tm++)
            af[tm] = *(const bf16x8*)(&Ps[(tm * 16 + lcol) * PT + lk + ks * 32]);
#pragma unroll
        for (int tn = 0; tn < 2; tn++)
            vf[tn] = *(const bf16x8*)(&Vt[(tn * 16 + lcol) * VT + lk + ks * 32]);
#pragma unroll
        for (int tm = 0; tm < 4; tm++)
#pragma unroll
            for (int tn = 0; tn < 2; tn++)
                o[tm][tn] = __builtin_amdgcn_mfma_f32_16x16x32_bf16(
                    af[tm], vf[tn], o[tm][tn], 0, 0, 0);
    }

    bf16* ob = aout + (size_t)(win * 64) * 512 + head * 32;
#pragma unroll
    for (int tm = 0; tm < 4; tm++)
#pragma unroll
        for (int tn = 0; tn < 2; tn++)
#pragma unroll
            for (int r = 0; r < 4; r++) {
                int m = tm * 16 + quad * 4 + r;
                ob[(size_t)m * 512 + tn * 16 + lcol] =
                    (bf16)(o[tm][tn][r] * rinv[tm][r]);
            }
}

// ---------------- x1 = x + LN(proj_out)*w+b -------------------------------------
__global__ __launch_bounds__(64) void ln_res_k(const bf16* __restrict__ xin,
                                               const bf16* __restrict__ pin,
                                               const bf16* __restrict__ w,
                                               const bf16* __restrict__ b,
                                               bf16* __restrict__ x1)
{
    int row = blockIdx.x, lane = threadIdx.x;
    bf16x8 pv = *(const bf16x8*)(pin + (size_t)row * 512 + lane * 8);
    float v[8]; float s = 0.f;
#pragma unroll
    for (int i = 0; i < 8; i++) { v[i] = (float)pv[i]; s += v[i]; }
#pragma unroll
    for (int o = 32; o >= 1; o >>= 1) s += __shfl_xor(s, o);
    float mean = s * (1.f / 512.f);
    float vv = 0.f;
#pragma unroll
    for (int i = 0; i < 8; i++) { float d = v[i] - mean; vv += d * d; }
#pragma unroll
    for (int o = 32; o >= 1; o >>= 1) vv += __shfl_xor(vv, o);
    float rstd = rsqrtf(vv * (1.f / 512.f) + 1e-5f);
    bf16x8 xv = *(const bf16x8*)(xin + (size_t)row * 512 + lane * 8);
    bf16x8 wv = *(const bf16x8*)(w + lane * 8);
    bf16x8 bv = *(const bf16x8*)(b + lane * 8);
    bf16x8 ov;
#pragma unroll
    for (int i = 0; i < 8; i++) {
        float ln = (v[i] - mean) * rstd * (float)wv[i] + (float)bv[i];
        ov[i] = (bf16)((float)xv[i] + ln);
    }
    *(bf16x8*)(x1 + (size_t)row * 512 + lane * 8) = ov;
}

// ---------------- out(f32) = x1 + LN(moeAcc + sum_e wts_e*b2_e)*w+b -------------
__global__ __launch_bounds__(64) void final_k(const float* __restrict__ moe,
                                              const bf16* __restrict__ x1,
                                              const bf16* __restrict__ w,
                                              const bf16* __restrict__ b,
                                              const float* __restrict__ wts,
                                              const bf16* __restrict__ b2,
                                              float* __restrict__ out)
{
    int row = blockIdx.x, lane = threadIdx.x;
    float w0 = wts[row * 4 + 0], w1 = wts[row * 4 + 1],
          w2 = wts[row * 4 + 2], w3 = wts[row * 4 + 3];
    const float4* mr = (const float4*)(moe + (size_t)row * 512 + lane * 8);
    float4 m0 = mr[0], m1 = mr[1];
    float v[8] = {m0.x, m0.y, m0.z, m0.w, m1.x, m1.y, m1.z, m1.w};
    bf16x8 b20 = *(const bf16x8*)(b2 + lane * 8);
    bf16x8 b21 = *(const bf16x8*)(b2 + 512 + lane * 8);
    bf16x8 b22 = *(const bf16x8*)(b2 + 1024 + lane * 8);
    bf16x8 b23 = *(const bf16x8*)(b2 + 1536 + lane * 8);
    float s = 0.f;
#pragma unroll
    for (int i = 0; i < 8; i++) {
        v[i] += w0 * (float)b20[i] + w1 * (float)b21[i]
              + w2 * (float)b22[i] + w3 * (float)b23[i];
        s += v[i];
    }
#pragma unroll
    for (int o = 32; o >= 1; o >>= 1) s += __shfl_xor(s, o);
    float mean = s * (1.f / 512.f);
    float vv = 0.f;
#pragma unroll
    for (int i = 0; i < 8; i++) { float d = v[i] - mean; vv += d * d; }
#pragma unroll
    for (int o = 32; o >= 1; o >>= 1) vv += __shfl_xor(vv, o);
    float rstd = rsqrtf(vv * (1.f / 512.f) + 1e-5f);
    bf16x8 xv = *(const bf16x8*)(x1 + (size_t)row * 512 + lane * 8);
    bf16x8 wv = *(const bf16x8*)(w + lane * 8);
    bf16x8 bv = *(const bf16x8*)(b + lane * 8);
    float ot[8];
#pragma unroll
    for (int i = 0; i < 8; i++) {
        float ln = (v[i] - mean) * rstd * (float)wv[i] + (float)bv[i];
        ot[i] = (float)xv[i] + ln;
    }
    float4* op = (float4*)(out + (size_t)row * 512 + lane * 8);
    op[0] = (float4){ot[0], ot[1], ot[2], ot[3]};
    op[1] = (float4){ot[4], ot[5], ot[6], ot[7]};
}

// ---------------- gate ----------------------------------------------------------
__global__ __launch_bounds__(64) void gate_k(const float* __restrict__ fa,
                                             const bf16* __restrict__ g,
                                             const bf16* __restrict__ w2,
                                             const bf16* __restrict__ b2,
                                             float* __restrict__ wts)
{
    int row = blockIdx.x, lane = threadIdx.x;
    const float* fr = fa + (size_t)row * 256;
    float a[4]; float mx = -1e30f;
#pragma unroll
    for (int i = 0; i < 4; i++) { a[i] = fr[lane * 4 + i]; mx = fmaxf(mx, a[i]); }
#pragma unroll
    for (int o = 32; o >= 1; o >>= 1) mx = fmaxf(mx, __shfl_xor(mx, o));
    float sum = 0.f;
#pragma unroll
    for (int i = 0; i < 4; i++) { a[i] = expf(a[i] - mx); sum += a[i]; }
#pragma unroll
    for (int o = 32; o >= 1; o >>= 1) sum += __shfl_xor(sum, o);
    float inv = 1.f / sum;
    float gb[4];
#pragma unroll
    for (int i = 0; i < 4; i++)
        gb[i] = a[i] * inv * (float)g[(size_t)row * 256 + lane * 4 + i];
    float lg[4];
#pragma unroll
    for (int j = 0; j < 4; j++) {
        float p = 0.f;
#pragma unroll
        for (int i = 0; i < 4; i++) p += gb[i] * (float)w2[j * 256 + lane * 4 + i];
        lg[j] = p;
    }
#pragma unroll
    for (int o = 32; o >= 1; o >>= 1) {
#pragma unroll
        for (int j = 0; j < 4; j++) lg[j] += __shfl_xor(lg[j], o);
    }
    if (lane == 0) {
        float m2 = -1e30f;
#pragma unroll
        for (int j = 0; j < 4; j++) { lg[j] += (float)b2[j]; m2 = fmaxf(m2, lg[j]); }
        float s2 = 0.f; float e2[4];
#pragma unroll
        for (int j = 0; j < 4; j++) { e2[j] = expf(lg[j] - m2); s2 += e2[j]; }
#pragma unroll
        for (int j = 0; j < 4; j++) wts[(size_t)row * 4 + j] = e2[j] / s2;
    }
}

extern "C" void kernel_launch(void* const* d_in, const int* in_sizes, int n_in,
                              void* d_out, int out_size, void* d_ws, size_t ws_size,
                              hipStream_t stream)
{
    float* out = (float*)d_out;
    char* ws = (char*)d_ws;
    const size_t MB = 1024ull * 1024ull;

    static const int sizes[NIN] = {
        16777216, 786432, 512, 512, 16, 1024, 512, 8192, 262144, 512,
        512, 512, 512, 512, 4194304, 8192, 4194304, 2048,
        131072, 256, 65536, 256, 1024, 4, 262144, 512
    };
    ConvArgs ca;
    size_t off = 0;
    bf16* cp[NIN];
    for (int i = 1; i < NIN; i++) {
        cp[i] = (bf16*)(ws + off);
        off += ((size_t)sizes[i] * 2 + 255) & ~255ull;
    }
    cp[0] = (bf16*)(ws + 20 * MB);
    for (int i = 0; i < NIN; i++) {
        ca.src[i] = d_in[i];
        ca.dst[i] = cp[i];
        ca.n[i]   = sizes[i];
    }
    const bf16 *xc = cp[0], *qkv_w = cp[1], *q_bias = cp[2], *v_bias = cp[3],
               *lsc = cp[4], *cpb_w1 = cp[5], *cpb_b1 = cp[6], *cpb_w2 = cp[7],
               *proj_w = cp[8], *proj_b = cp[9], *n1w = cp[10], *n1b = cp[11],
               *n2w = cp[12], *n2b = cp[13], *exp_w1 = cp[14], *exp_b1 = cp[15],
               *exp_w2 = cp[16], *exp_b2 = cp[17], *gl1w = cp[18], *gl1b = cp[19],
               *gfaw = cp[20], *gfab = cp[21], *gl2w = cp[22], *gl2b = cp[23],
               *taskw = cp[24], *taskb = cp[25];

    // scratch arena (lifetime-overlapped; peak 182 MB)
    bf16*  qkv   = (bf16*)(ws + 53 * MB);
    bf16*  aout  = (bf16*)(ws + 149 * MB);
    bf16*  projo = (bf16*)(ws + 53 * MB);
    bf16*  x1    = (bf16*)(ws + 85 * MB);
    bf16*  tbuf  = (bf16*)(ws + 20 * MB);
    bf16*  gbuf  = (bf16*)(ws + 53 * MB);
    float* fabuf = (float*)(ws + 117 * MB);
    bf16*  hid   = (bf16*)(ws + 20 * MB);
    float* moe   = (float*)(ws + 117 * MB);
    int*   flag  = (int*)(ws + 181 * MB);
    float* wts   = (float*)(ws + 181 * MB + 4096);
    float* tbl   = (float*)(ws + 181 * MB + 4096 + 524288);

    probe_k<<<1, 256, 0, stream>>>((const unsigned short*)d_in[0], flag);
    conv_k<<<dim3(1024, NIN), 256, 0, stream>>>(ca, flag);

    cpb_k<<<225, 64, 0, stream>>>(cpb_w1, cpb_b1, cpb_w2, tbl);
    gemm_k<1, EPI_QKV><<<256 * 12, 256, 0, stream>>>(
        xc, qkv_w, qkv, q_bias, v_bias, nullptr, 1536, 512, 0, 256);
    attn_k<<<2048, 256, 0, stream>>>(qkv, lsc, tbl, aout);
    gemm_k<0, EPI_PROJ><<<256 * 4, 256, 0, stream>>>(
        aout, proj_w, projo, proj_b, nullptr, nullptr, 512, 512, 0, 256);
    ln_res_k<<<32768, 64, 0, stream>>>(xc, projo, n1w, n1b, x1);
    gemm_k<0, EPI_BF16><<<256 * 4, 256, 0, stream>>>(
        x1, taskw, tbuf, taskb, nullptr, nullptr, 512, 512, 0, 256);
    gemm_k<0, EPI_RELU><<<256 * 2, 256, 0, stream>>>(
        tbuf, gl1w, gbuf, gl1b, nullptr, nullptr, 256, 512, 0, 256);
    gemm_k<0, EPI_F32><<<256 * 2, 256, 0, stream>>>(
        gbuf, gfaw, fabuf, gfab, nullptr, nullptr, 256, 256, 0, 256);
    gate_k<<<32768, 64, 0, stream>>>(fabuf, gbuf, gl2w, gl2b, wts);
    // moe accumulator zero-init (after gate_k: moe region aliases fabuf)
    zero_k<<<2048, 256, 0, stream>>>((float4*)moe, 32768 * 512 / 4);
    for (int e = 0; e < 4; e++) {
        for (int h = 0; h < 2; h++) {
            const size_t ro = (size_t)h * 16384;
            gemm_k<0, EPI_GELU><<<128 * 16, 256, 0, stream>>>(
                x1 + ro * 512, exp_w1 + (size_t)e * 2048 * 512, hid,
                exp_b1 + e * 2048, nullptr, wts + ro * 4, 2048, 512, e, 128);
            // split-K=2: 1024 blocks (4/CU vs 2/CU) to cover the per-K-step
            // vmcnt(0)+barrier drain; halves accumulate via f32 atomics.
            gemm_k<0, EPI_MOE, 2><<<128 * 4 * 2, 256, 0, stream>>>(
                hid, exp_w2 + (size_t)e * 512 * 2048, moe + ro * 512,
                nullptr, nullptr, nullptr, 512, 2048, e, 128);
        }
    }
    final_k<<<32768, 64, 0, stream>>>(moe, x1, n2w, n2b, wts, exp_b2, out);
}

// Round 2
// 1135.888 us; speedup vs baseline: 1.4686x; 1.4686x over previous
//
#include <hip/hip_runtime.h>
#include <math.h>

typedef __bf16 bf16;
typedef bf16 bf16x8 __attribute__((ext_vector_type(8)));
typedef bf16 bf16x4_t __attribute__((ext_vector_type(4)));
typedef float f32x4 __attribute__((ext_vector_type(4)));

// B=8, H=W=64, DIM=512, WS=8, SHIFT=4, NH=16, HD=32, N=64, nW=64, M=32768
// NE=4, HID=2048, GH=256. Inputs f32 (proven R2->R3), output f32 (proven R3->R4).
// R1 post-mortem: MOE atomic split-K regressed -213us (134M L2 atomics) -> reverted.
// Fast tanh-GELU kept (validated: absmax unchanged, passed).

#define EPI_QKV  0
#define EPI_PROJ 1
#define EPI_BF16 2
#define EPI_RELU 3
#define EPI_F32  4
#define EPI_GELU 5
#define EPI_MOE  6

#define NIN 26

#define GLDS16(gp, lp)                                                    \
    __builtin_amdgcn_global_load_lds(                                     \
        (const __attribute__((address_space(1))) void*)(gp),              \
        (__attribute__((address_space(3))) void*)(lp), 16, 0, 0)

// ---------------- dtype probe ---------------------------------------------------
__global__ __launch_bounds__(256) void probe_k(const unsigned short* __restrict__ x,
                                               int* __restrict__ flag)
{
    __shared__ int cnt[256];
    int t = threadIdx.x;
    int bad = 0;
    for (int j = t; j < 4096; j += 256) {
        int e = (x[j] >> 7) & 0xFF;
        if (e >= 132) bad++;
    }
    cnt[t] = bad;
    __syncthreads();
    for (int s = 128; s > 0; s >>= 1) {
        if (t < s) cnt[t] += cnt[t + s];
        __syncthreads();
    }
    if (t == 0) *flag = (cnt[0] > 64) ? 1 : 0;
}

// ---------------- convert all inputs to bf16 in ws ------------------------------
struct ConvArgs {
    const void* src[NIN];
    bf16* dst[NIN];
    int n[NIN];
};

__global__ __launch_bounds__(256) void conv_k(ConvArgs a, const int* __restrict__ flag)
{
    int i = blockIdx.y;
    int n4 = a.n[i] >> 2;
    bf16x4_t* dst = (bf16x4_t*)a.dst[i];
    int stride = gridDim.x * 256;
    if (*flag) {
        const float4* s = (const float4*)a.src[i];
        for (int j = blockIdx.x * 256 + threadIdx.x; j < n4; j += stride) {
            float4 v = s[j];
            dst[j] = (bf16x4_t){(bf16)v.x, (bf16)v.y, (bf16)v.z, (bf16)v.w};
        }
    } else {
        const bf16x4_t* s = (const bf16x4_t*)a.src[i];
        for (int j = blockIdx.x * 256 + threadIdx.x; j < n4; j += stride)
            dst[j] = s[j];
    }
}

// shift + window-partition row map (self-inverse composition: roll -4 then +4)
__device__ __forceinline__ int win_remap(int r) {
    int win = r >> 6, tok = r & 63;
    int b = win >> 6, wi = win & 63;
    int h = (((wi >> 3) << 3) + (tok >> 3) + 4) & 63;
    int w = (((wi & 7) << 3) + (tok & 7) + 4) & 63;
    return (b << 12) | (h << 6) | w;
}

// ---------------- MFMA GEMM, BK=64, swizzled LDS, XCD-aware grid ----------------
// C[m][n] = sum_k A[m][k]*W[n][k] (+epilogue). 128x128 tile, 4 waves 2x2.
// LDS tile: slot (row, cl) holds global chunk cg = cl ^ (row&7) (16B chunks).
// __launch_bounds__(256,4): cap regs at 128 (was ~144 unified incl. 64 acc) so
// 4 blocks/CU fit (LDS cap is 5) -> more inter-block overlap of the per-K-step
// vmcnt(0)+barrier drain. Occupancy was ~2-3 blocks/CU (28%), MfmaUtil 21%.
template<int REMAP_A, int EPI>
__global__ __launch_bounds__(256, 4) void gemm_k(
    const bf16* __restrict__ A, const bf16* __restrict__ Bw,
    void* __restrict__ Cout,
    const bf16* __restrict__ bias, const bf16* __restrict__ bias2,
    const float* __restrict__ wts, int N, int K, int eIdx, int nbm)
{
    __shared__ __attribute__((aligned(16))) bf16 As[128 * 64];
    __shared__ __attribute__((aligned(16))) bf16 Bs[128 * 64];
    const int tid = threadIdx.x;

    // XCD-aware swizzle: xcd = lin&7 gets bm = xcd+8*(...), sweeping bn fastest
    // over groups of G A-tiles -> per-XCD A-tile L2 reuse across the bn sweep.
    const int lin = blockIdx.x;
    const int nbn = N >> 7;
    const int xcd = lin & 7, s = lin >> 3;
    const int nbmx = nbm >> 3;
    const int G = nbmx < 16 ? nbmx : 16;
    const int gsz = G * nbn;
    const int gi = s / gsz, rem = s - gi * gsz;
    const int bn = rem / G, bmi = rem - bn * G;
    const int bm = xcd + 8 * (gi * G + bmi);

    const int wave = tid >> 6, lane = tid & 63;
    const int wm = (wave >> 1) << 6, wn = (wave & 1) << 6;
    const int lrow = lane & 15, quad = lane >> 4;

    // staging: thread -> (row sr=tid>>3 [+32*i], LDS chunk slot sc=tid&7);
    // fetches global chunk scg = sc ^ (sr&7). LDS dest = i*4096B + tid*16B.
    const int sr = tid >> 3, sc = tid & 7;
    const int scg = sc ^ (sr & 7);
    int ga[4];
#pragma unroll
    for (int i = 0; i < 4; i++) {
        int r = bm * 128 + sr + i * 32;
        ga[i] = REMAP_A ? win_remap(r) : r;
    }
    const int brow = bn * 128 + sr;
    bf16* lA = As + tid * 8;
    bf16* lB = Bs + tid * 8;

    f32x4 acc[4][4];
#pragma unroll
    for (int i = 0; i < 4; i++)
#pragma unroll
        for (int j = 0; j < 4; j++) acc[i][j] = (f32x4){0.f, 0.f, 0.f, 0.f};

    for (int k0 = 0; k0 < K; k0 += 64) {
        __syncthreads();
#pragma unroll
        for (int i = 0; i < 4; i++) {
            GLDS16(A + (size_t)ga[i] * K + k0 + scg * 8, lA + i * 2048);
            GLDS16(Bw + (size_t)(brow + i * 32) * K + k0 + scg * 8, lB + i * 2048);
        }
        __syncthreads();
#pragma unroll
        for (int ks = 0; ks < 2; ks++) {
            bf16x8 af[4], bfr[4];
#pragma unroll
            for (int t = 0; t < 4; t++) {
                int ra = wm + t * 16 + lrow;
                af[t] = *(const bf16x8*)(&As[ra * 64 + (((ks << 2) + quad) ^ (ra & 7)) * 8]);
                int rb = wn + t * 16 + lrow;
                bfr[t] = *(const bf16x8*)(&Bs[rb * 64 + (((ks << 2) + quad) ^ (rb & 7)) * 8]);
            }
#pragma unroll
            for (int tm = 0; tm < 4; tm++)
#pragma unroll
                for (int tn = 0; tn < 4; tn++)
                    acc[tm][tn] = __builtin_amdgcn_mfma_f32_16x16x32_bf16(
                        af[tm], bfr[tn], acc[tm][tn], 0, 0, 0);
        }
    }

    const int cr0 = quad << 2, cc0 = lane & 15;
#pragma unroll
    for (int tm = 0; tm < 4; tm++) {
#pragma unroll
        for (int tn = 0; tn < 4; tn++) {
#pragma unroll
            for (int r = 0; r < 4; r++) {
                int row = bm * 128 + wm + tm * 16 + cr0 + r;
                int col = bn * 128 + wn + tn * 16 + cc0;
                float v = acc[tm][tn][r];
                if constexpr (EPI == EPI_QKV) {
                    float bv = 0.f;
                    if (col < 512) bv = (float)bias[col];
                    else if (col >= 1024) bv = (float)bias2[col - 1024];
                    ((bf16*)Cout)[(size_t)row * N + col] = (bf16)(v + bv);
                } else if constexpr (EPI == EPI_PROJ) {
                    v += (float)bias[col];
                    ((bf16*)Cout)[(size_t)win_remap(row) * N + col] = (bf16)v;
                } else if constexpr (EPI == EPI_BF16) {
                    v += (float)bias[col];
                    ((bf16*)Cout)[(size_t)row * N + col] = (bf16)v;
                } else if constexpr (EPI == EPI_RELU) {
                    v += (float)bias[col];
                    ((bf16*)Cout)[(size_t)row * N + col] = (bf16)fmaxf(v, 0.f);
                } else if constexpr (EPI == EPI_F32) {
                    v += (float)bias[col];
                    ((float*)Cout)[(size_t)row * N + col] = v;
                } else if constexpr (EPI == EPI_GELU) {
                    // hid = wts[row,e] * gelu(v + b1); wts folded here so the
                    // second gemm is a pure accumulation.
                    // tanh-form GELU (validated R1: absmax unchanged): branch-free
                    // ~8 VALU + v_exp + v_rcp vs erff's ~30+ branchy ops.
                    v += (float)bias[col];
                    float u = 1.5957691216f * v * fmaf(0.044715f * v, v, 1.0f);
                    float g = v * __builtin_amdgcn_rcpf(1.0f + __expf(-u));
                    g *= wts[(size_t)row * 4 + eIdx];
                    ((bf16*)Cout)[(size_t)row * N + col] = (bf16)g;
                } else if constexpr (EPI == EPI_MOE) {
                    // sequential expert accumulation (R1 lesson: atomics -213us)
                    float* p = &((float*)Cout)[(size_t)row * N + col];
                    if (eIdx == 0) *p = v; else *p += v;
                }
            }
        }
    }
}

// ---------------- CPB table -----------------------------------------------------
__global__ __launch_bounds__(64) void cpb_k(const bf16* __restrict__ w1,
                                            const bf16* __restrict__ b1,
                                            const bf16* __restrict__ w2,
                                            float* __restrict__ tbl)
{
    int e = blockIdx.x;
    int d0 = e / 15, d1 = e % 15;
    auto f = [](int d) -> float {
        float v = (float)(d - 7) * (8.0f / 7.0f);
        float t = log2f(fabsf(v) + 1.0f) * (1.0f / 3.0f);
        return v < 0.f ? -t : (v > 0.f ? t : 0.0f);
    };
    float t0 = f(d0), t1 = f(d1);
    __shared__ float hsh[512];
    int tid = threadIdx.x;
    for (int j = tid; j < 512; j += 64) {
        float h = t0 * (float)w1[j * 2 + 0] + t1 * (float)w1[j * 2 + 1] + (float)b1[j];
        hsh[j] = fmaxf(h, 0.0f);
    }
    __syncthreads();
    if (tid < 16) {
        float sum = 0.f;
        for (int j = 0; j < 512; j++) sum += hsh[j] * (float)w2[tid * 512 + j];
        tbl[e * 16 + tid] = 16.0f / (1.0f + expf(-sum));
    }
}

// ---------------- MFMA attention ------------------------------------------------
#define PT 72
#define VT 72
__global__ __launch_bounds__(256) void attn_k(const bf16* __restrict__ qkv,
                                              const bf16* __restrict__ lsc,
                                              const float* __restrict__ tbl,
                                              bf16* __restrict__ aout)
{
    __shared__ __attribute__((aligned(16))) bf16 VtAll[4][32 * VT];
    __shared__ __attribute__((aligned(16))) bf16 PsAll[4][64 * PT];
    const int tid  = threadIdx.x;
    const int wave = tid >> 6, lane = tid & 63;
    const int pair = blockIdx.x * 4 + wave;
    const int win  = pair >> 4, head = pair & 15;
    bf16* Vt = VtAll[wave];
    bf16* Ps = PsAll[wave];

    const int lcol = lane & 15;
    const int quad = lane >> 4;
    const int lk   = quad << 3;

    const bf16* qbase = qkv + (size_t)(win * 64) * 1536 + head * 32;

    {
        const bf16* vp = qbase + (size_t)lane * 1536 + 1024;
        bf16x8 v0 = *(const bf16x8*)(vp);
        bf16x8 v1 = *(const bf16x8*)(vp + 8);
        bf16x8 v2 = *(const bf16x8*)(vp + 16);
        bf16x8 v3 = *(const bf16x8*)(vp + 24);
#pragma unroll
        for (int j = 0; j < 8; j++) {
            Vt[(j)      * VT + lane] = v0[j];
            Vt[(j + 8)  * VT + lane] = v1[j];
            Vt[(j + 16) * VT + lane] = v2[j];
            Vt[(j + 24) * VT + lane] = v3[j];
        }
    }

    bf16x8 qf[4], kf[4];
#pragma unroll
    for (int t = 0; t < 4; t++) {
        const bf16* qp = qbase + (size_t)(t * 16 + lcol) * 1536 + lk;
        bf16x8 q = *(const bf16x8*)qp;
        float ss = 0.f;
#pragma unroll
        for (int j = 0; j < 8; j++) { float f = (float)q[j]; ss += f * f; }
        ss += __shfl_xor(ss, 16); ss += __shfl_xor(ss, 32);
        float inv = 1.f / fmaxf(sqrtf(ss), 1e-12f);
#pragma unroll
        for (int j = 0; j < 8; j++) q[j] = (bf16)((float)q[j] * inv);
        qf[t] = q;

        const bf16* kp = qbase + (size_t)(t * 16 + lcol) * 1536 + 512 + lk;
        bf16x8 k = *(const bf16x8*)kp;
        ss = 0.f;
#pragma unroll
        for (int j = 0; j < 8; j++) { float f = (float)k[j]; ss += f * f; }
        ss += __shfl_xor(ss, 16); ss += __shfl_xor(ss, 32);
        inv = 1.f / fmaxf(sqrtf(ss), 1e-12f);
#pragma unroll
        for (int j = 0; j < 8; j++) k[j] = (bf16)((float)k[j] * inv);
        kf[t] = k;
    }

    f32x4 s[4][4];
#pragma unroll
    for (int tm = 0; tm < 4; tm++)
#pragma unroll
        for (int tn = 0; tn < 4; tn++) s[tm][tn] = (f32x4){0.f, 0.f, 0.f, 0.f};
#pragma unroll
    for (int tm = 0; tm < 4; tm++)
#pragma unroll
        for (int tn = 0; tn < 4; tn++)
            s[tm][tn] = __builtin_amdgcn_mfma_f32_16x16x32_bf16(
                qf[tm], kf[tn], s[tm][tn], 0, 0, 0);

    float scale = expf(fminf((float)lsc[head], 4.6051701860f));
    int wi = win & 63, wh = wi >> 3, ww = wi & 7;
    float rinv[4][4];
#pragma unroll
    for (int tm = 0; tm < 4; tm++) {
#pragma unroll
        for (int r = 0; r < 4; r++) {
            int m = tm * 16 + quad * 4 + r;
            int qi = m >> 3, qj = m & 7;
            int qh = wh * 8 + qi, qw = ww * 8 + qj;
            int qid = (qh < 56 ? 0 : (qh < 60 ? 1 : 2)) * 3 +
                      (qw < 56 ? 0 : (qw < 60 ? 1 : 2));
            float v[4]; float mx = -1e30f;
#pragma unroll
            for (int tn = 0; tn < 4; tn++) {
                int n = tn * 16 + lcol;
                int ki = n >> 3, kj = n & 7;
                int kh = wh * 8 + ki, kw = ww * 8 + kj;
                int kid = (kh < 56 ? 0 : (kh < 60 ? 1 : 2)) * 3 +
                          (kw < 56 ? 0 : (kw < 60 ? 1 : 2));
                float val = s[tm][tn][r] * scale
                          + tbl[((qi - ki + 7) * 15 + (qj - kj + 7)) * 16 + head];
                if (kid != qid) val -= 100.f;
                v[tn] = val;
                mx = fmaxf(mx, val);
            }
            mx = fmaxf(mx, __shfl_xor(mx, 1));
            mx = fmaxf(mx, __shfl_xor(mx, 2));
            mx = fmaxf(mx, __shfl_xor(mx, 4));
            mx = fmaxf(mx, __shfl_xor(mx, 8));
            float sum = 0.f;
#pragma unroll
            for (int tn = 0; tn < 4; tn++) {
                float p = expf(v[tn] - mx);
                v[tn] = p; sum += p;
            }
            sum += __shfl_xor(sum, 1);
            sum += __shfl_xor(sum, 2);
            sum += __shfl_xor(sum, 4);
            sum += __shfl_xor(sum, 8);
            rinv[tm][r] = 1.f / sum;
#pragma unroll
            for (int tn = 0; tn < 4; tn++)
                Ps[m * PT + tn * 16 + lcol] = (bf16)v[tn];
        }
    }
    __syncthreads();

    f32x4 o[4][2];
#pragma unroll
    for (int tm = 0; tm < 4; tm++)
#pragma unroll
        for (int tn = 0; tn < 2; tn++) o[tm][tn] = (f32x4){0.f, 0.f, 0.f, 0.f};
#pragma unroll
    for (int ks = 0; ks < 2; ks++) {
        bf16x8 af[4], vf[2];
#pragma unroll
        for (int tm = 0; tm < 4; tm++)
            af[tm] = *(const bf16x8*)(&Ps[(tm * 16 + lcol) * PT + lk + ks * 32]);
#pragma unroll
        for (int tn = 0; tn < 2; tn++)
            vf[tn] = *(const bf16x8*)(&Vt[(tn * 16 + lcol) * VT + lk + ks * 32]);
#pragma unroll
        for (int tm = 0; tm < 4; tm++)
#pragma unroll
            for (int tn = 0; tn < 2; tn++)
                o[tm][tn] = __builtin_amdgcn_mfma_f32_16x16x32_bf16(
                    af[tm], vf[tn], o[tm][tn], 0, 0, 0);
    }

    bf16* ob = aout + (size_t)(win * 64) * 512 + head * 32;
#pragma unroll
    for (int tm = 0; tm < 4; tm++)
#pragma unroll
        for (int tn = 0; tn < 2; tn++)
#pragma unroll
            for (int r = 0; r < 4; r++) {
                int m = tm * 16 + quad * 4 + r;
                ob[(size_t)m * 512 + tn * 16 + lcol] =
                    (bf16)(o[tm][tn][r] * rinv[tm][r]);
            }
}

// ---------------- x1 = x + LN(proj_out)*w+b -------------------------------------
// NOTE: x1 may alias xin (in-place): each lane reads its own 16B before writing
// the same 16B; no cross-row deps -> RAW-safe.
__global__ __launch_bounds__(64) void ln_res_k(const bf16* __restrict__ xin,
                                               const bf16* __restrict__ pin,
                                               const bf16* __restrict__ w,
                                               const bf16* __restrict__ b,
                                               bf16* __restrict__ x1)
{
    int row = blockIdx.x, lane = threadIdx.x;
    bf16x8 pv = *(const bf16x8*)(pin + (size_t)row * 512 + lane * 8);
    float v[8]; float s = 0.f;
#pragma unroll
    for (int i = 0; i < 8; i++) { v[i] = (float)pv[i]; s += v[i]; }
#pragma unroll
    for (int o = 32; o >= 1; o >>= 1) s += __shfl_xor(s, o);
    float mean = s * (1.f / 512.f);
    float vv = 0.f;
#pragma unroll
    for (int i = 0; i < 8; i++) { float d = v[i] - mean; vv += d * d; }
#pragma unroll
    for (int o = 32; o >= 1; o >>= 1) vv += __shfl_xor(vv, o);
    float rstd = rsqrtf(vv * (1.f / 512.f) + 1e-5f);
    bf16x8 xv = *(const bf16x8*)(xin + (size_t)row * 512 + lane * 8);
    bf16x8 wv = *(const bf16x8*)(w + lane * 8);
    bf16x8 bv = *(const bf16x8*)(b + lane * 8);
    bf16x8 ov;
#pragma unroll
    for (int i = 0; i < 8; i++) {
        float ln = (v[i] - mean) * rstd * (float)wv[i] + (float)bv[i];
        ov[i] = (bf16)((float)xv[i] + ln);
    }
    *(bf16x8*)(x1 + (size_t)row * 512 + lane * 8) = ov;
}

// ---------------- out(f32) = x1 + LN(moeAcc + sum_e wts_e*b2_e)*w+b -------------
__global__ __launch_bounds__(64) void final_k(const float* __restrict__ moe,
                                              const bf16* __restrict__ x1,
                                              const bf16* __restrict__ w,
                                              const bf16* __restrict__ b,
                                              const float* __restrict__ wts,
                                              const bf16* __restrict__ b2,
                                              float* __restrict__ out)
{
    int row = blockIdx.x, lane = threadIdx.x;
    float w0 = wts[row * 4 + 0], w1 = wts[row * 4 + 1],
          w2 = wts[row * 4 + 2], w3 = wts[row * 4 + 3];
    const float4* mr = (const float4*)(moe + (size_t)row * 512 + lane * 8);
    float4 m0 = mr[0], m1 = mr[1];
    float v[8] = {m0.x, m0.y, m0.z, m0.w, m1.x, m1.y, m1.z, m1.w};
    bf16x8 b20 = *(const bf16x8*)(b2 + lane * 8);
    bf16x8 b21 = *(const bf16x8*)(b2 + 512 + lane * 8);
    bf16x8 b22 = *(const bf16x8*)(b2 + 1024 + lane * 8);
    bf16x8 b23 = *(const bf16x8*)(b2 + 1536 + lane * 8);
    float s = 0.f;
#pragma unroll
    for (int i = 0; i < 8; i++) {
        v[i] += w0 * (float)b20[i] + w1 * (float)b21[i]
              + w2 * (float)b22[i] + w3 * (float)b23[i];
        s += v[i];
    }
#pragma unroll
    for (int o = 32; o >= 1; o >>= 1) s += __shfl_xor(s, o);
    float mean = s * (1.f / 512.f);
    float vv = 0.f;
#pragma unroll
    for (int i = 0; i < 8; i++) { float d = v[i] - mean; vv += d * d; }
#pragma unroll
    for (int o = 32; o >= 1; o >>= 1) vv += __shfl_xor(vv, o);
    float rstd = rsqrtf(vv * (1.f / 512.f) + 1e-5f);
    bf16x8 xv = *(const bf16x8*)(x1 + (size_t)row * 512 + lane * 8);
    bf16x8 wv = *(const bf16x8*)(w + lane * 8);
    bf16x8 bv = *(const bf16x8*)(b + lane * 8);
    float ot[8];
#pragma unroll
    for (int i = 0; i < 8; i++) {
        float ln = (v[i] - mean) * rstd * (float)wv[i] + (float)bv[i];
        ot[i] = (float)xv[i] + ln;
    }
    float4* op = (float4*)(out + (size_t)row * 512 + lane * 8);
    op[0] = (float4){ot[0], ot[1], ot[2], ot[3]};
    op[1] = (float4){ot[4], ot[5], ot[6], ot[7]};
}

// ---------------- gate ----------------------------------------------------------
__global__ __launch_bounds__(64) void gate_k(const float* __restrict__ fa,
                                             const bf16* __restrict__ g,
                                             const bf16* __restrict__ w2,
                                             const bf16* __restrict__ b2,
                                             float* __restrict__ wts)
{
    int row = blockIdx.x, lane = threadIdx.x;
    const float* fr = fa + (size_t)row * 256;
    float a[4]; float mx = -1e30f;
#pragma unroll
    for (int i = 0; i < 4; i++) { a[i] = fr[lane * 4 + i]; mx = fmaxf(mx, a[i]); }
#pragma unroll
    for (int o = 32; o >= 1; o >>= 1) mx = fmaxf(mx, __shfl_xor(mx, o));
    float sum = 0.f;
#pragma unroll
    for (int i = 0; i < 4; i++) { a[i] = expf(a[i] - mx); sum += a[i]; }
#pragma unroll
    for (int o = 32; o >= 1; o >>= 1) sum += __shfl_xor(sum, o);
    float inv = 1.f / sum;
    float gb[4];
#pragma unroll
    for (int i = 0; i < 4; i++)
        gb[i] = a[i] * inv * (float)g[(size_t)row * 256 + lane * 4 + i];
    float lg[4];
#pragma unroll
    for (int j = 0; j < 4; j++) {
        float p = 0.f;
#pragma unroll
        for (int i = 0; i < 4; i++) p += gb[i] * (float)w2[j * 256 + lane * 4 + i];
        lg[j] = p;
    }
#pragma unroll
    for (int o = 32; o >= 1; o >>= 1) {
#pragma unroll
        for (int j = 0; j < 4; j++) lg[j] += __shfl_xor(lg[j], o);
    }
    if (lane == 0) {
        float m2 = -1e30f;
#pragma unroll
        for (int j = 0; j < 4; j++) { lg[j] += (float)b2[j]; m2 = fmaxf(m2, lg[j]); }
        float s2 = 0.f; float e2[4];
#pragma unroll
        for (int j = 0; j < 4; j++) { e2[j] = expf(lg[j] - m2); s2 += e2[j]; }
#pragma unroll
        for (int j = 0; j < 4; j++) wts[(size_t)row * 4 + j] = e2[j] / s2;
    }
}

extern "C" void kernel_launch(void* const* d_in, const int* in_sizes, int n_in,
                              void* d_out, int out_size, void* d_ws, size_t ws_size,
                              hipStream_t stream)
{
    float* out = (float*)d_out;
    char* ws = (char*)d_ws;
    const size_t MB = 1024ull * 1024ull;

    static const int sizes[NIN] = {
        16777216, 786432, 512, 512, 16, 1024, 512, 8192, 262144, 512,
        512, 512, 512, 512, 4194304, 8192, 4194304, 2048,
        131072, 256, 65536, 256, 1024, 4, 262144, 512
    };
    ConvArgs ca;
    size_t off = 0;
    bf16* cp[NIN];
    for (int i = 1; i < NIN; i++) {
        cp[i] = (bf16*)(ws + off);
        off += ((size_t)sizes[i] * 2 + 255) & ~255ull;
    }
    cp[0] = (bf16*)(ws + 20 * MB);
    for (int i = 0; i < NIN; i++) {
        ca.src[i] = d_in[i];
        ca.dst[i] = cp[i];
        ca.n[i]   = sizes[i];
    }
    const bf16 *xc = cp[0], *qkv_w = cp[1], *q_bias = cp[2], *v_bias = cp[3],
               *lsc = cp[4], *cpb_w1 = cp[5], *cpb_b1 = cp[6], *cpb_w2 = cp[7],
               *proj_w = cp[8], *proj_b = cp[9], *n1w = cp[10], *n1b = cp[11],
               *n2w = cp[12], *n2b = cp[13], *exp_w1 = cp[14], *exp_b1 = cp[15],
               *exp_w2 = cp[16], *exp_b2 = cp[17], *gl1w = cp[18], *gl1b = cp[19],
               *gfaw = cp[20], *gfab = cp[21], *gl2w = cp[22], *gl2b = cp[23],
               *taskw = cp[24], *taskb = cp[25];

    // scratch arena v2 (lifetime-overlapped):
    //  [0,20)   converted weights
    //  [20,52)  xc, then x1 in-place (ln_res per-lane RAW-safe)
    //  [53,149) qkv -> projo[53,85) -> tbuf[53,85) -> hid
    //  [85,101) gbuf   [101,133) fabuf(f32)
    //  [149,181) aout
    //  [181,182) flag/wts/tbl
    //  bigws (ws>=246MB): hid[53,181) full-M 128MB, moe(f32)[182,246)
    //  else: hid[53,117) half-M, moe(f32)[117,181)
    bf16*  qkv   = (bf16*)(ws + 53 * MB);
    bf16*  aout  = (bf16*)(ws + 149 * MB);
    bf16*  projo = (bf16*)(ws + 53 * MB);
    bf16*  x1    = (bf16*)(ws + 20 * MB);   // in-place over xc
    bf16*  tbuf  = (bf16*)(ws + 53 * MB);
    bf16*  gbuf  = (bf16*)(ws + 85 * MB);
    float* fabuf = (float*)(ws + 101 * MB);
    int*   flag  = (int*)(ws + 181 * MB);
    float* wts   = (float*)(ws + 181 * MB + 4096);
    float* tbl   = (float*)(ws + 181 * MB + 4096 + 524288);

    const bool bigws = ws_size >= 246 * MB;
    bf16*  hid = (bf16*)(ws + 53 * MB);
    float* moe = bigws ? (float*)(ws + 182 * MB) : (float*)(ws + 117 * MB);

    probe_k<<<1, 256, 0, stream>>>((const unsigned short*)d_in[0], flag);
    conv_k<<<dim3(1024, NIN), 256, 0, stream>>>(ca, flag);

    cpb_k<<<225, 64, 0, stream>>>(cpb_w1, cpb_b1, cpb_w2, tbl);
    gemm_k<1, EPI_QKV><<<256 * 12, 256, 0, stream>>>(
        xc, qkv_w, qkv, q_bias, v_bias, nullptr, 1536, 512, 0, 256);
    attn_k<<<2048, 256, 0, stream>>>(qkv, lsc, tbl, aout);
    gemm_k<0, EPI_PROJ><<<256 * 4, 256, 0, stream>>>(
        aout, proj_w, projo, proj_b, nullptr, nullptr, 512, 512, 0, 256);
    ln_res_k<<<32768, 64, 0, stream>>>(xc, projo, n1w, n1b, x1);
    gemm_k<0, EPI_BF16><<<256 * 4, 256, 0, stream>>>(
        x1, taskw, tbuf, taskb, nullptr, nullptr, 512, 512, 0, 256);
    gemm_k<0, EPI_RELU><<<256 * 2, 256, 0, stream>>>(
        tbuf, gl1w, gbuf, gl1b, nullptr, nullptr, 256, 512, 0, 256);
    gemm_k<0, EPI_F32><<<256 * 2, 256, 0, stream>>>(
        gbuf, gfaw, fabuf, gfab, nullptr, nullptr, 256, 256, 0, 256);
    gate_k<<<32768, 64, 0, stream>>>(fabuf, gbuf, gl2w, gl2b, wts);

    if (bigws) {
        // full-M expert path: hid 128MB, MOE grid 1024 blocks (4/CU-worth vs 2)
        for (int e = 0; e < 4; e++) {
            gemm_k<0, EPI_GELU><<<256 * 16, 256, 0, stream>>>(
                x1, exp_w1 + (size_t)e * 2048 * 512, hid,
                exp_b1 + e * 2048, nullptr, wts, 2048, 512, e, 256);
            gemm_k<0, EPI_MOE><<<256 * 4, 256, 0, stream>>>(
                hid, exp_w2 + (size_t)e * 512 * 2048, moe,
                nullptr, nullptr, nullptr, 512, 2048, e, 256);
        }
    } else {
        for (int e = 0; e < 4; e++) {
            for (int h = 0; h < 2; h++) {
                const size_t ro = (size_t)h * 16384;
                gemm_k<0, EPI_GELU><<<128 * 16, 256, 0, stream>>>(
                    x1 + ro * 512, exp_w1 + (size_t)e * 2048 * 512, hid,
                    exp_b1 + e * 2048, nullptr, wts + ro * 4, 2048, 512, e, 128);
                gemm_k<0, EPI_MOE><<<128 * 4, 256, 0, stream>>>(
                    hid, exp_w2 + (size_t)e * 512 * 2048, moe + ro * 512,
                    nullptr, nullptr, nullptr, 512, 2048, e, 128);
            }
        }
    }
    final_k<<<32768, 64, 0, stream>>>(moe, x1, n2w, n2b, wts, exp_b2, out);
}

// Round 4
// 1134.634 us; speedup vs baseline: 1.4702x; 1.0011x over previous
//
#include <hip/hip_runtime.h>
#include <math.h>

typedef __bf16 bf16;
typedef bf16 bf16x8 __attribute__((ext_vector_type(8)));
typedef bf16 bf16x4_t __attribute__((ext_vector_type(4)));
typedef float f32x4 __attribute__((ext_vector_type(4)));

// B=8, H=W=64, DIM=512, WS=8, SHIFT=4, NH=16, HD=32, N=64, nW=64, M=32768
// NE=4, HID=2048, GH=256. Inputs f32 (proven R2->R3), output f32 (proven R3->R4).
// R1: MOE atomic split-K regressed (-213us, 134M L2 atomics) -> reverted.
// R2: launch_bounds(256,4) + full-M experts -> 1136us.
// R3: attn overhaul (mask table, no max-sub, 1-wave blocks) FAILED: mbt was
//     placed at ws+101MB INSIDE qkv's [53,149MB) extent -> QKV gemm trashed it.
// R4: mbt moved to the 1MB hole at [52,53)MB (xc ends 52, qkv starts 53).

#define EPI_QKV  0
#define EPI_PROJ 1
#define EPI_BF16 2
#define EPI_RELU 3
#define EPI_F32  4
#define EPI_GELU 5
#define EPI_MOE  6

#define NIN 26

#define GLDS16(gp, lp)                                                    \
    __builtin_amdgcn_global_load_lds(                                     \
        (const __attribute__((address_space(1))) void*)(gp),              \
        (__attribute__((address_space(3))) void*)(lp), 16, 0, 0)

// ---------------- dtype probe ---------------------------------------------------
__global__ __launch_bounds__(256) void probe_k(const unsigned short* __restrict__ x,
                                               int* __restrict__ flag)
{
    __shared__ int cnt[256];
    int t = threadIdx.x;
    int bad = 0;
    for (int j = t; j < 4096; j += 256) {
        int e = (x[j] >> 7) & 0xFF;
        if (e >= 132) bad++;
    }
    cnt[t] = bad;
    __syncthreads();
    for (int s = 128; s > 0; s >>= 1) {
        if (t < s) cnt[t] += cnt[t + s];
        __syncthreads();
    }
    if (t == 0) *flag = (cnt[0] > 64) ? 1 : 0;
}

// ---------------- convert all inputs to bf16 in ws ------------------------------
struct ConvArgs {
    const void* src[NIN];
    bf16* dst[NIN];
    int n[NIN];
};

__global__ __launch_bounds__(256) void conv_k(ConvArgs a, const int* __restrict__ flag)
{
    int i = blockIdx.y;
    int n4 = a.n[i] >> 2;
    bf16x4_t* dst = (bf16x4_t*)a.dst[i];
    int stride = gridDim.x * 256;
    if (*flag) {
        const float4* s = (const float4*)a.src[i];
        for (int j = blockIdx.x * 256 + threadIdx.x; j < n4; j += stride) {
            float4 v = s[j];
            dst[j] = (bf16x4_t){(bf16)v.x, (bf16)v.y, (bf16)v.z, (bf16)v.w};
        }
    } else {
        const bf16x4_t* s = (const bf16x4_t*)a.src[i];
        for (int j = blockIdx.x * 256 + threadIdx.x; j < n4; j += stride)
            dst[j] = s[j];
    }
}

// shift + window-partition row map (self-inverse composition: roll -4 then +4)
__device__ __forceinline__ int win_remap(int r) {
    int win = r >> 6, tok = r & 63;
    int b = win >> 6, wi = win & 63;
    int h = (((wi >> 3) << 3) + (tok >> 3) + 4) & 63;
    int w = (((wi & 7) << 3) + (tok & 7) + 4) & 63;
    return (b << 12) | (h << 6) | w;
}

// ---------------- MFMA GEMM, BK=64, swizzled LDS, XCD-aware grid ----------------
// C[m][n] = sum_k A[m][k]*W[n][k] (+epilogue). 128x128 tile, 4 waves 2x2.
// LDS tile: slot (row, cl) holds global chunk cg = cl ^ (row&7) (16B chunks).
// __launch_bounds__(256,4): 4 blocks/CU (R2: +25% occ, validated win).
template<int REMAP_A, int EPI>
__global__ __launch_bounds__(256, 4) void gemm_k(
    const bf16* __restrict__ A, const bf16* __restrict__ Bw,
    void* __restrict__ Cout,
    const bf16* __restrict__ bias, const bf16* __restrict__ bias2,
    const float* __restrict__ wts, int N, int K, int eIdx, int nbm)
{
    __shared__ __attribute__((aligned(16))) bf16 As[128 * 64];
    __shared__ __attribute__((aligned(16))) bf16 Bs[128 * 64];
    const int tid = threadIdx.x;

    // XCD-aware swizzle: xcd = lin&7 gets bm = xcd+8*(...), sweeping bn fastest
    // over groups of G A-tiles -> per-XCD A-tile L2 reuse across the bn sweep.
    const int lin = blockIdx.x;
    const int nbn = N >> 7;
    const int xcd = lin & 7, s = lin >> 3;
    const int nbmx = nbm >> 3;
    const int G = nbmx < 16 ? nbmx : 16;
    const int gsz = G * nbn;
    const int gi = s / gsz, rem = s - gi * gsz;
    const int bn = rem / G, bmi = rem - bn * G;
    const int bm = xcd + 8 * (gi * G + bmi);

    const int wave = tid >> 6, lane = tid & 63;
    const int wm = (wave >> 1) << 6, wn = (wave & 1) << 6;
    const int lrow = lane & 15, quad = lane >> 4;

    // staging: thread -> (row sr=tid>>3 [+32*i], LDS chunk slot sc=tid&7);
    // fetches global chunk scg = sc ^ (sr&7). LDS dest = i*4096B + tid*16B.
    const int sr = tid >> 3, sc = tid & 7;
    const int scg = sc ^ (sr & 7);
    int ga[4];
#pragma unroll
    for (int i = 0; i < 4; i++) {
        int r = bm * 128 + sr + i * 32;
        ga[i] = REMAP_A ? win_remap(r) : r;
    }
    const int brow = bn * 128 + sr;
    bf16* lA = As + tid * 8;
    bf16* lB = Bs + tid * 8;

    f32x4 acc[4][4];
#pragma unroll
    for (int i = 0; i < 4; i++)
#pragma unroll
        for (int j = 0; j < 4; j++) acc[i][j] = (f32x4){0.f, 0.f, 0.f, 0.f};

    for (int k0 = 0; k0 < K; k0 += 64) {
        __syncthreads();
#pragma unroll
        for (int i = 0; i < 4; i++) {
            GLDS16(A + (size_t)ga[i] * K + k0 + scg * 8, lA + i * 2048);
            GLDS16(Bw + (size_t)(brow + i * 32) * K + k0 + scg * 8, lB + i * 2048);
        }
        __syncthreads();
#pragma unroll
        for (int ks = 0; ks < 2; ks++) {
            bf16x8 af[4], bfr[4];
#pragma unroll
            for (int t = 0; t < 4; t++) {
                int ra = wm + t * 16 + lrow;
                af[t] = *(const bf16x8*)(&As[ra * 64 + (((ks << 2) + quad) ^ (ra & 7)) * 8]);
                int rb = wn + t * 16 + lrow;
                bfr[t] = *(const bf16x8*)(&Bs[rb * 64 + (((ks << 2) + quad) ^ (rb & 7)) * 8]);
            }
#pragma unroll
            for (int tm = 0; tm < 4; tm++)
#pragma unroll
                for (int tn = 0; tn < 4; tn++)
                    acc[tm][tn] = __builtin_amdgcn_mfma_f32_16x16x32_bf16(
                        af[tm], bfr[tn], acc[tm][tn], 0, 0, 0);
        }
    }

    const int cr0 = quad << 2, cc0 = lane & 15;
#pragma unroll
    for (int tm = 0; tm < 4; tm++) {
#pragma unroll
        for (int tn = 0; tn < 4; tn++) {
#pragma unroll
            for (int r = 0; r < 4; r++) {
                int row = bm * 128 + wm + tm * 16 + cr0 + r;
                int col = bn * 128 + wn + tn * 16 + cc0;
                float v = acc[tm][tn][r];
                if constexpr (EPI == EPI_QKV) {
                    float bv = 0.f;
                    if (col < 512) bv = (float)bias[col];
                    else if (col >= 1024) bv = (float)bias2[col - 1024];
                    ((bf16*)Cout)[(size_t)row * N + col] = (bf16)(v + bv);
                } else if constexpr (EPI == EPI_PROJ) {
                    v += (float)bias[col];
                    ((bf16*)Cout)[(size_t)win_remap(row) * N + col] = (bf16)v;
                } else if constexpr (EPI == EPI_BF16) {
                    v += (float)bias[col];
                    ((bf16*)Cout)[(size_t)row * N + col] = (bf16)v;
                } else if constexpr (EPI == EPI_RELU) {
                    v += (float)bias[col];
                    ((bf16*)Cout)[(size_t)row * N + col] = (bf16)fmaxf(v, 0.f);
                } else if constexpr (EPI == EPI_F32) {
                    v += (float)bias[col];
                    ((float*)Cout)[(size_t)row * N + col] = v;
                } else if constexpr (EPI == EPI_GELU) {
                    // hid = wts[row,e] * gelu(v + b1); wts folded here so the
                    // second gemm is a pure accumulation.
                    // tanh-form GELU (validated R1: absmax unchanged).
                    v += (float)bias[col];
                    float u = 1.5957691216f * v * fmaf(0.044715f * v, v, 1.0f);
                    float g = v * __builtin_amdgcn_rcpf(1.0f + __expf(-u));
                    g *= wts[(size_t)row * 4 + eIdx];
                    ((bf16*)Cout)[(size_t)row * N + col] = (bf16)g;
                } else if constexpr (EPI == EPI_MOE) {
                    // sequential expert accumulation (R1 lesson: atomics -213us)
                    float* p = &((float*)Cout)[(size_t)row * N + col];
                    if (eIdx == 0) *p = v; else *p += v;
                }
            }
        }
    }
}

// ---------------- CPB table -----------------------------------------------------
__global__ __launch_bounds__(64) void cpb_k(const bf16* __restrict__ w1,
                                            const bf16* __restrict__ b1,
                                            const bf16* __restrict__ w2,
                                            float* __restrict__ tbl)
{
    int e = blockIdx.x;
    int d0 = e / 15, d1 = e % 15;
    auto f = [](int d) -> float {
        float v = (float)(d - 7) * (8.0f / 7.0f);
        float t = log2f(fabsf(v) + 1.0f) * (1.0f / 3.0f);
        return v < 0.f ? -t : (v > 0.f ? t : 0.0f);
    };
    float t0 = f(d0), t1 = f(d1);
    __shared__ float hsh[512];
    int tid = threadIdx.x;
    for (int j = tid; j < 512; j += 64) {
        float h = t0 * (float)w1[j * 2 + 0] + t1 * (float)w1[j * 2 + 1] + (float)b1[j];
        hsh[j] = fmaxf(h, 0.0f);
    }
    __syncthreads();
    if (tid < 16) {
        float sum = 0.f;
        for (int j = 0; j < 512; j++) sum += hsh[j] * (float)w2[tid * 512 + j];
        tbl[e * 16 + tid] = 16.0f / (1.0f + expf(-sum));
    }
}

// ---------------- expand bias+mask: mbt[cls(2x2)][head][64][64] f32 -------------
// cls = eh*2+ew; eh/ew = window touches image edge in h/w (wh==7 / ww==7).
// mask(q,k) = -100 if region(q) != region(k); regions (shifted frame):
// h<56 -> 0, 56..59 -> 1, 60..63 -> 2. Edge window rows are 56+qi.
__global__ __launch_bounds__(256) void expand_k(const float* __restrict__ tbl,
                                                float* __restrict__ mbt)
{
    int head = blockIdx.x & 15, cls = blockIdx.x >> 4;
    int eh = cls >> 1, ew = cls & 1;
    for (int idx = threadIdx.x; idx < 4096; idx += 256) {
        int m = idx >> 6, n = idx & 63;
        int qi = m >> 3, qj = m & 7, ki = n >> 3, kj = n & 7;
        float bias = tbl[((qi - ki + 7) * 15 + (qj - kj + 7)) * 16 + head];
        int qid = (eh ? (qi < 4 ? 1 : 2) : 0) * 3 + (ew ? (qj < 4 ? 1 : 2) : 0);
        int kid = (eh ? (ki < 4 ? 1 : 2) : 0) * 3 + (ew ? (kj < 4 ? 1 : 2) : 0);
        mbt[(size_t)blockIdx.x * 4096 + idx] = bias + (qid != kid ? -100.f : 0.f);
    }
}

// ---------------- MFMA attention, 1 wave/block ----------------------------------
// R3: LDS 13.8KB/block -> ~11 blocks/CU (was 55KB -> 2). Inner loop: coalesced
// f32 load from precomputed mbt (no qid/kid branches, no tbl gather), no
// max-subtraction (logits bounded: |s|<=1 * scale<=10 + bias<16, mask -100
// -> exp range [~0, e^26], safe in f32; unnormalized p stored bf16).
#define PT 72
#define VT 72
__global__ __launch_bounds__(64) void attn_k(const bf16* __restrict__ qkv,
                                             const bf16* __restrict__ lsc,
                                             const float* __restrict__ mbt,
                                             bf16* __restrict__ aout)
{
    __shared__ __attribute__((aligned(16))) bf16 Vt[32 * VT];
    __shared__ __attribute__((aligned(16))) bf16 Ps[64 * PT];
    const int lane = threadIdx.x;
    const int pair = blockIdx.x;
    const int win  = pair >> 4, head = pair & 15;

    const int lcol = lane & 15;
    const int quad = lane >> 4;
    const int lk   = quad << 3;

    const bf16* qbase = qkv + (size_t)(win * 64) * 1536 + head * 32;

    {
        const bf16* vp = qbase + (size_t)lane * 1536 + 1024;
        bf16x8 v0 = *(const bf16x8*)(vp);
        bf16x8 v1 = *(const bf16x8*)(vp + 8);
        bf16x8 v2 = *(const bf16x8*)(vp + 16);
        bf16x8 v3 = *(const bf16x8*)(vp + 24);
#pragma unroll
        for (int j = 0; j < 8; j++) {
            Vt[(j)      * VT + lane] = v0[j];
            Vt[(j + 8)  * VT + lane] = v1[j];
            Vt[(j + 16) * VT + lane] = v2[j];
            Vt[(j + 24) * VT + lane] = v3[j];
        }
    }

    bf16x8 qf[4], kf[4];
#pragma unroll
    for (int t = 0; t < 4; t++) {
        const bf16* qp = qbase + (size_t)(t * 16 + lcol) * 1536 + lk;
        bf16x8 q = *(const bf16x8*)qp;
        float ss = 0.f;
#pragma unroll
        for (int j = 0; j < 8; j++) { float f = (float)q[j]; ss += f * f; }
        ss += __shfl_xor(ss, 16); ss += __shfl_xor(ss, 32);
        float inv = 1.f / fmaxf(sqrtf(ss), 1e-12f);
#pragma unroll
        for (int j = 0; j < 8; j++) q[j] = (bf16)((float)q[j] * inv);
        qf[t] = q;

        const bf16* kp = qbase + (size_t)(t * 16 + lcol) * 1536 + 512 + lk;
        bf16x8 k = *(const bf16x8*)kp;
        ss = 0.f;
#pragma unroll
        for (int j = 0; j < 8; j++) { float f = (float)k[j]; ss += f * f; }
        ss += __shfl_xor(ss, 16); ss += __shfl_xor(ss, 32);
        inv = 1.f / fmaxf(sqrtf(ss), 1e-12f);
#pragma unroll
        for (int j = 0; j < 8; j++) k[j] = (bf16)((float)k[j] * inv);
        kf[t] = k;
    }

    f32x4 s[4][4];
#pragma unroll
    for (int tm = 0; tm < 4; tm++)
#pragma unroll
        for (int tn = 0; tn < 4; tn++) s[tm][tn] = (f32x4){0.f, 0.f, 0.f, 0.f};
#pragma unroll
    for (int tm = 0; tm < 4; tm++)
#pragma unroll
        for (int tn = 0; tn < 4; tn++)
            s[tm][tn] = __builtin_amdgcn_mfma_f32_16x16x32_bf16(
                qf[tm], kf[tn], s[tm][tn], 0, 0, 0);

    float scale = expf(fminf((float)lsc[head], 4.6051701860f));
    int wi = win & 63, wh = wi >> 3, ww = wi & 7;
    const float* Tb = mbt +
        (((size_t)(((wh == 7) ? 2 : 0) + ((ww == 7) ? 1 : 0)) * 16 + head) << 12);
    float rinv[4][4];
#pragma unroll
    for (int tm = 0; tm < 4; tm++) {
#pragma unroll
        for (int r = 0; r < 4; r++) {
            int m = tm * 16 + quad * 4 + r;
            const float* Tm = Tb + m * 64 + lcol;
            float p0 = __expf(fmaf(s[tm][0][r], scale, Tm[0]));
            float p1 = __expf(fmaf(s[tm][1][r], scale, Tm[16]));
            float p2 = __expf(fmaf(s[tm][2][r], scale, Tm[32]));
            float p3 = __expf(fmaf(s[tm][3][r], scale, Tm[48]));
            float sum = (p0 + p1) + (p2 + p3);
            sum += __shfl_xor(sum, 1);
            sum += __shfl_xor(sum, 2);
            sum += __shfl_xor(sum, 4);
            sum += __shfl_xor(sum, 8);
            rinv[tm][r] = __builtin_amdgcn_rcpf(sum);
            Ps[m * PT + 0  + lcol] = (bf16)p0;
            Ps[m * PT + 16 + lcol] = (bf16)p1;
            Ps[m * PT + 32 + lcol] = (bf16)p2;
            Ps[m * PT + 48 + lcol] = (bf16)p3;
        }
    }
    __syncthreads();

    f32x4 o[4][2];
#pragma unroll
    for (int tm = 0; tm < 4; tm++)
#pragma unroll
        for (int tn = 0; tn < 2; tn++) o[tm][tn] = (f32x4){0.f, 0.f, 0.f, 0.f};
#pragma unroll
    for (int ks = 0; ks < 2; ks++) {
        bf16x8 af[4], vf[2];
#pragma unroll
        for (int tm = 0; tm < 4; tm++)
            af[tm] = *(const bf16x8*)(&Ps[(tm * 16 + lcol) * PT + lk + ks * 32]);
#pragma unroll
        for (int tn = 0; tn < 2; tn++)
            vf[tn] = *(const bf16x8*)(&Vt[(tn * 16 + lcol) * VT + lk + ks * 32]);
#pragma unroll
        for (int tm = 0; tm < 4; tm++)
#pragma unroll
            for (int tn = 0; tn < 2; tn++)
                o[tm][tn] = __builtin_amdgcn_mfma_f32_16x16x32_bf16(
                    af[tm], vf[tn], o[tm][tn], 0, 0, 0);
    }

    bf16* ob = aout + (size_t)(win * 64) * 512 + head * 32;
#pragma unroll
    for (int tm = 0; tm < 4; tm++)
#pragma unroll
        for (int tn = 0; tn < 2; tn++)
#pragma unroll
            for (int r = 0; r < 4; r++) {
                int m = tm * 16 + quad * 4 + r;
                ob[(size_t)m * 512 + tn * 16 + lcol] =
                    (bf16)(o[tm][tn][r] * rinv[tm][r]);
            }
}

// ---------------- x1 = x + LN(proj_out)*w+b -------------------------------------
// NOTE: x1 may alias xin (in-place): each lane reads its own 16B before writing
// the same 16B; no cross-row deps -> RAW-safe.
__global__ __launch_bounds__(64) void ln_res_k(const bf16* __restrict__ xin,
                                               const bf16* __restrict__ pin,
                                               const bf16* __restrict__ w,
                                               const bf16* __restrict__ b,
                                               bf16* __restrict__ x1)
{
    int row = blockIdx.x, lane = threadIdx.x;
    bf16x8 pv = *(const bf16x8*)(pin + (size_t)row * 512 + lane * 8);
    float v[8]; float s = 0.f;
#pragma unroll
    for (int i = 0; i < 8; i++) { v[i] = (float)pv[i]; s += v[i]; }
#pragma unroll
    for (int o = 32; o >= 1; o >>= 1) s += __shfl_xor(s, o);
    float mean = s * (1.f / 512.f);
    float vv = 0.f;
#pragma unroll
    for (int i = 0; i < 8; i++) { float d = v[i] - mean; vv += d * d; }
#pragma unroll
    for (int o = 32; o >= 1; o >>= 1) vv += __shfl_xor(vv, o);
    float rstd = rsqrtf(vv * (1.f / 512.f) + 1e-5f);
    bf16x8 xv = *(const bf16x8*)(xin + (size_t)row * 512 + lane * 8);
    bf16x8 wv = *(const bf16x8*)(w + lane * 8);
    bf16x8 bv = *(const bf16x8*)(b + lane * 8);
    bf16x8 ov;
#pragma unroll
    for (int i = 0; i < 8; i++) {
        float ln = (v[i] - mean) * rstd * (float)wv[i] + (float)bv[i];
        ov[i] = (bf16)((float)xv[i] + ln);
    }
    *(bf16x8*)(x1 + (size_t)row * 512 + lane * 8) = ov;
}

// ---------------- out(f32) = x1 + LN(moeAcc + sum_e wts_e*b2_e)*w+b -------------
__global__ __launch_bounds__(64) void final_k(const float* __restrict__ moe,
                                              const bf16* __restrict__ x1,
                                              const bf16* __restrict__ w,
                                              const bf16* __restrict__ b,
                                              const float* __restrict__ wts,
                                              const bf16* __restrict__ b2,
                                              float* __restrict__ out)
{
    int row = blockIdx.x, lane = threadIdx.x;
    float w0 = wts[row * 4 + 0], w1 = wts[row * 4 + 1],
          w2 = wts[row * 4 + 2], w3 = wts[row * 4 + 3];
    const float4* mr = (const float4*)(moe + (size_t)row * 512 + lane * 8);
    float4 m0 = mr[0], m1 = mr[1];
    float v[8] = {m0.x, m0.y, m0.z, m0.w, m1.x, m1.y, m1.z, m1.w};
    bf16x8 b20 = *(const bf16x8*)(b2 + lane * 8);
    bf16x8 b21 = *(const bf16x8*)(b2 + 512 + lane * 8);
    bf16x8 b22 = *(const bf16x8*)(b2 + 1024 + lane * 8);
    bf16x8 b23 = *(const bf16x8*)(b2 + 1536 + lane * 8);
    float s = 0.f;
#pragma unroll
    for (int i = 0; i < 8; i++) {
        v[i] += w0 * (float)b20[i] + w1 * (float)b21[i]
              + w2 * (float)b22[i] + w3 * (float)b23[i];
        s += v[i];
    }
#pragma unroll
    for (int o = 32; o >= 1; o >>= 1) s += __shfl_xor(s, o);
    float mean = s * (1.f / 512.f);
    float vv = 0.f;
#pragma unroll
    for (int i = 0; i < 8; i++) { float d = v[i] - mean; vv += d * d; }
#pragma unroll
    for (int o = 32; o >= 1; o >>= 1) vv += __shfl_xor(vv, o);
    float rstd = rsqrtf(vv * (1.f / 512.f) + 1e-5f);
    bf16x8 xv = *(const bf16x8*)(x1 + (size_t)row * 512 + lane * 8);
    bf16x8 wv = *(const bf16x8*)(w + lane * 8);
    bf16x8 bv = *(const bf16x8*)(b + lane * 8);
    float ot[8];
#pragma unroll
    for (int i = 0; i < 8; i++) {
        float ln = (v[i] - mean) * rstd * (float)wv[i] + (float)bv[i];
        ot[i] = (float)xv[i] + ln;
    }
    float4* op = (float4*)(out + (size_t)row * 512 + lane * 8);
    op[0] = (float4){ot[0], ot[1], ot[2], ot[3]};
    op[1] = (float4){ot[4], ot[5], ot[6], ot[7]};
}

// ---------------- gate ----------------------------------------------------------
__global__ __launch_bounds__(64) void gate_k(const float* __restrict__ fa,
                                             const bf16* __restrict__ g,
                                             const bf16* __restrict__ w2,
                                             const bf16* __restrict__ b2,
                                             float* __restrict__ wts)
{
    int row = blockIdx.x, lane = threadIdx.x;
    const float* fr = fa + (size_t)row * 256;
    float a[4]; float mx = -1e30f;
#pragma unroll
    for (int i = 0; i < 4; i++) { a[i] = fr[lane * 4 + i]; mx = fmaxf(mx, a[i]); }
#pragma unroll
    for (int o = 32; o >= 1; o >>= 1) mx = fmaxf(mx, __shfl_xor(mx, o));
    float sum = 0.f;
#pragma unroll
    for (int i = 0; i < 4; i++) { a[i] = expf(a[i] - mx); sum += a[i]; }
#pragma unroll
    for (int o = 32; o >= 1; o >>= 1) sum += __shfl_xor(sum, o);
    float inv = 1.f / sum;
    float gb[4];
#pragma unroll
    for (int i = 0; i < 4; i++)
        gb[i] = a[i] * inv * (float)g[(size_t)row * 256 + lane * 4 + i];
    float lg[4];
#pragma unroll
    for (int j = 0; j < 4; j++) {
        float p = 0.f;
#pragma unroll
        for (int i = 0; i < 4; i++) p += gb[i] * (float)w2[j * 256 + lane * 4 + i];
        lg[j] = p;
    }
#pragma unroll
    for (int o = 32; o >= 1; o >>= 1) {
#pragma unroll
        for (int j = 0; j < 4; j++) lg[j] += __shfl_xor(lg[j], o);
    }
    if (lane == 0) {
        float m2 = -1e30f;
#pragma unroll
        for (int j = 0; j < 4; j++) { lg[j] += (float)b2[j]; m2 = fmaxf(m2, lg[j]); }
        float s2 = 0.f; float e2[4];
#pragma unroll
        for (int j = 0; j < 4; j++) { e2[j] = expf(lg[j] - m2); s2 += e2[j]; }
#pragma unroll
        for (int j = 0; j < 4; j++) wts[(size_t)row * 4 + j] = e2[j] / s2;
    }
}

extern "C" void kernel_launch(void* const* d_in, const int* in_sizes, int n_in,
                              void* d_out, int out_size, void* d_ws, size_t ws_size,
                              hipStream_t stream)
{
    float* out = (float*)d_out;
    char* ws = (char*)d_ws;
    const size_t MB = 1024ull * 1024ull;

    static const int sizes[NIN] = {
        16777216, 786432, 512, 512, 16, 1024, 512, 8192, 262144, 512,
        512, 512, 512, 512, 4194304, 8192, 4194304, 2048,
        131072, 256, 65536, 256, 1024, 4, 262144, 512
    };
    ConvArgs ca;
    size_t off = 0;
    bf16* cp[NIN];
    for (int i = 1; i < NIN; i++) {
        cp[i] = (bf16*)(ws + off);
        off += ((size_t)sizes[i] * 2 + 255) & ~255ull;
    }
    cp[0] = (bf16*)(ws + 20 * MB);
    for (int i = 0; i < NIN; i++) {
        ca.src[i] = d_in[i];
        ca.dst[i] = cp[i];
        ca.n[i]   = sizes[i];
    }
    const bf16 *xc = cp[0], *qkv_w = cp[1], *q_bias = cp[2], *v_bias = cp[3],
               *lsc = cp[4], *cpb_w1 = cp[5], *cpb_b1 = cp[6], *cpb_w2 = cp[7],
               *proj_w = cp[8], *proj_b = cp[9], *n1w = cp[10], *n1b = cp[11],
               *n2w = cp[12], *n2b = cp[13], *exp_w1 = cp[14], *exp_b1 = cp[15],
               *exp_w2 = cp[16], *exp_b2 = cp[17], *gl1w = cp[18], *gl1b = cp[19],
               *gfaw = cp[20], *gfab = cp[21], *gl2w = cp[22], *gl2b = cp[23],
               *taskw = cp[24], *taskb = cp[25];

    // scratch arena v3 (lifetime-overlapped):
    //  [0,20)   converted weights
    //  [20,52)  xc, then x1 in-place (ln_res per-lane RAW-safe)
    //  [52,53)  mbt (1MB exactly) -- hole between xc and qkv; NOTHING else
    //           touches it (qkv starts at 53; R3 bug: mbt@101 was inside qkv)
    //  [53,149) qkv -> projo[53,85) -> tbuf[53,85) -> hid
    //  [85,101) gbuf   [101,133) fabuf(f32)
    //  [149,181) aout
    //  [181,182) flag/wts/tbl
    //  bigws (ws>=246MB): hid[53,181) full-M 128MB, moe(f32)[182,246)
    //  else: hid[53,117) half-M, moe(f32)[117,181)
    bf16*  qkv   = (bf16*)(ws + 53 * MB);
    bf16*  aout  = (bf16*)(ws + 149 * MB);
    bf16*  projo = (bf16*)(ws + 53 * MB);
    bf16*  x1    = (bf16*)(ws + 20 * MB);   // in-place over xc
    bf16*  tbuf  = (bf16*)(ws + 53 * MB);
    bf16*  gbuf  = (bf16*)(ws + 85 * MB);
    float* fabuf = (float*)(ws + 101 * MB);
    float* mbt   = (float*)(ws + 52 * MB);  // [52,53) hole, safe across QKV gemm
    int*   flag  = (int*)(ws + 181 * MB);
    float* wts   = (float*)(ws + 181 * MB + 4096);
    float* tbl   = (float*)(ws + 181 * MB + 4096 + 524288);

    const bool bigws = ws_size >= 246 * MB;
    bf16*  hid = (bf16*)(ws + 53 * MB);
    float* moe = bigws ? (float*)(ws + 182 * MB) : (float*)(ws + 117 * MB);

    probe_k<<<1, 256, 0, stream>>>((const unsigned short*)d_in[0], flag);
    conv_k<<<dim3(1024, NIN), 256, 0, stream>>>(ca, flag);

    cpb_k<<<225, 64, 0, stream>>>(cpb_w1, cpb_b1, cpb_w2, tbl);
    expand_k<<<64, 256, 0, stream>>>(tbl, mbt);
    gemm_k<1, EPI_QKV><<<256 * 12, 256, 0, stream>>>(
        xc, qkv_w, qkv, q_bias, v_bias, nullptr, 1536, 512, 0, 256);
    attn_k<<<8192, 64, 0, stream>>>(qkv, lsc, mbt, aout);
    gemm_k<0, EPI_PROJ><<<256 * 4, 256, 0, stream>>>(
        aout, proj_w, projo, proj_b, nullptr, nullptr, 512, 512, 0, 256);
    ln_res_k<<<32768, 64, 0, stream>>>(xc, projo, n1w, n1b, x1);
    gemm_k<0, EPI_BF16><<<256 * 4, 256, 0, stream>>>(
        x1, taskw, tbuf, taskb, nullptr, nullptr, 512, 512, 0, 256);
    gemm_k<0, EPI_RELU><<<256 * 2, 256, 0, stream>>>(
        tbuf, gl1w, gbuf, gl1b, nullptr, nullptr, 256, 512, 0, 256);
    gemm_k<0, EPI_F32><<<256 * 2, 256, 0, stream>>>(
        gbuf, gfaw, fabuf, gfab, nullptr, nullptr, 256, 256, 0, 256);
    gate_k<<<32768, 64, 0, stream>>>(fabuf, gbuf, gl2w, gl2b, wts);

    if (bigws) {
        // full-M expert path: hid 128MB, MOE grid 1024 blocks (R2 win)
        for (int e = 0; e < 4; e++) {
            gemm_k<0, EPI_GELU><<<256 * 16, 256, 0, stream>>>(
                x1, exp_w1 + (size_t)e * 2048 * 512, hid,
                exp_b1 + e * 2048, nullptr, wts, 2048, 512, e, 256);
            gemm_k<0, EPI_MOE><<<256 * 4, 256, 0, stream>>>(
                hid, exp_w2 + (size_t)e * 512 * 2048, moe,
                nullptr, nullptr, nullptr, 512, 2048, e, 256);
        }
    } else {
        for (int e = 0; e < 4; e++) {
            for (int h = 0; h < 2; h++) {
                const size_t ro = (size_t)h * 16384;
                gemm_k<0, EPI_GELU><<<128 * 16, 256, 0, stream>>>(
                    x1 + ro * 512, exp_w1 + (size_t)e * 2048 * 512, hid,
                    exp_b1 + e * 2048, nullptr, wts + ro * 4, 2048, 512, e, 128);
                gemm_k<0, EPI_MOE><<<128 * 4, 256, 0, stream>>>(
                    hid, exp_w2 + (size_t)e * 512 * 2048, moe + ro * 512,
                    nullptr, nullptr, nullptr, 512, 2048, e, 128);
            }
        }
    }
    final_k<<<32768, 64, 0, stream>>>(moe, x1, n2w, n2b, wts, exp_b2, out);
}